// Round 6
// baseline (377.311 us; speedup 1.0000x reference)
//
#include <hip/hip_runtime.h>

typedef float v4f __attribute__((ext_vector_type(4)));

// Problem constants
#define B_ 128
#define T_ 197
#define D_ 768
#define E_ 8
#define R_ 8
#define O_ 2304

// d_out flat layout (fp32 elements), in reference return order
#define NWU      (128LL * 197LL * 2304LL)      // weighted_update
#define OFF_RL   (NWU)                          // router_logits: 128*8
#define OFF_SEL  (OFF_RL + 1024LL)              // selected_experts: 128 (as float)
#define OFF_EW   (OFF_SEL + 128LL)              // expert_weights: 128*8
#define OFF_IMP  (OFF_EW + 1024LL)              // importance: 8
#define OFF_LOAD (OFF_IMP + 8LL)                // load: 8

// ---------------------------------------------------------------------------
// Kernel 1: partial token sums over T-chunks, float4-vectorized.
// partials live in the WU region of d_out (consumed by `route` before
// fused_lora overwrites the region).  part[(b*4+c)*768 + d]
// Also zero-inits the importance/load accumulators (16 floats).
// ---------------------------------------------------------------------------
__global__ void pool_partial(const float* __restrict__ tokens,
                             float* __restrict__ out) {
    int c   = blockIdx.x;          // 0..3
    int b   = blockIdx.y;          // 0..127
    int tid = threadIdx.x;         // 0..191  (float4 column)
    if (c == 0 && b == 0 && tid < 16) out[OFF_IMP + tid] = 0.0f;
    int t0 = c * 50;
    int t1 = t0 + 50; if (t1 > T_) t1 = T_;
    const float4* tp = (const float4*)(tokens + (long long)b * T_ * D_);
    float4 acc; acc.x = 0.f; acc.y = 0.f; acc.z = 0.f; acc.w = 0.f;
    for (int t = t0; t < t1; ++t) {
        float4 v = tp[t * 192 + tid];
        acc.x += v.x; acc.y += v.y; acc.z += v.z; acc.w += v.w;
    }
    ((float4*)out)[(long long)(b * 4 + c) * 192 + tid] = acc;
}

// ---------------------------------------------------------------------------
// Kernel 2: routing + stats.  One block per batch row.
// stats (importance/load) folded in via device-scope atomicAdd.
// ---------------------------------------------------------------------------
__global__ void route(const float* __restrict__ part,
                      const float* __restrict__ w_gate,
                      float* __restrict__ out) {
    __shared__ float pooled[768];
    __shared__ float psum[64];
    __shared__ float logits[8];
    __shared__ int   sel_s;
    __shared__ float top1_s;
    __shared__ float m_s, inv_s;

    int b   = blockIdx.x;
    int tid = threadIdx.x;

    #pragma unroll
    for (int j = 0; j < 3; ++j) {
        int d = tid + j * 256;
        float s = part[(long long)(b * 4 + 0) * D_ + d]
                + part[(long long)(b * 4 + 1) * D_ + d]
                + part[(long long)(b * 4 + 2) * D_ + d]
                + part[(long long)(b * 4 + 3) * D_ + d];
        pooled[d] = s * (1.0f / 197.0f);
    }
    __syncthreads();

    if (tid < 64) {
        int e = tid & 7;
        int p = tid >> 3;
        float s = 0.f;
        int d0 = p * 96;
        for (int d = d0; d < d0 + 96; ++d) s += pooled[d] * w_gate[d * 8 + e];
        psum[tid] = s;
    }
    __syncthreads();

    if (tid < 8) {
        float s = 0.f;
        #pragma unroll
        for (int p = 0; p < 8; ++p) s += psum[p * 8 + tid];
        logits[tid] = s;
        out[OFF_RL + (long long)b * 8 + tid] = s;
    }
    __syncthreads();

    if (tid == 0) {
        float m = logits[0];
        int sel = 0;
        #pragma unroll
        for (int e = 1; e < 8; ++e)
            if (logits[e] > m) { m = logits[e]; sel = e; }   // first max wins
        float den = 0.f;
        #pragma unroll
        for (int e = 0; e < 8; ++e) den += expf(logits[e] - m);
        float t1v = 1.0f / den;
        sel_s  = sel;
        top1_s = t1v;
        m_s    = m;
        inv_s  = t1v;
        out[OFF_SEL + b] = (float)sel;
        atomicAdd(&out[OFF_IMP + sel], t1v);     // importance[sel] += top1
    }
    __syncthreads();

    if (tid < 8) {
        out[OFF_EW + (long long)b * 8 + tid] = (tid == sel_s) ? top1_s : 0.0f;
        // load[e] += softmax(logits)[e]
        atomicAdd(&out[OFF_LOAD + tid], expf(logits[tid] - m_s) * inv_s);
    }
}

// ---------------------------------------------------------------------------
// Kernel 3: fused  h = (tokens @ A[sel]) * gs  →  regs  →  wu = h @ Bw[sel].
//
// Round-6: round-5 structure with 8-row-deep groups (was 4).
//  - WU-phase Bw LDS traffic halves: 18 → 9 ds_read_b128 per row.
//  - h-phase issues 24 concurrent token dwordx4 loads per group (was 12)
//    — better HBM latency hiding.
//  - VGPR check (round-3 scar): hreg[8][8]=64 + 8 live v4f acc = 32 +
//    addressing ≈ 170 VGPR.  At 512 thr / launch_bounds(512,1) the cap is
//    256 (2 waves/SIMD) — no spill.  All arrays constant-indexed after
//    full unroll.
//  - Frozen invariants: As+Bw co-resident in LDS (96 KB, 1 block/CU,
//    stage once); h via __shfl_xor butterfly (no LDS round-trip, single
//    barrier); per-wave interleave of token reads and NT WU stores;
//    A NOT in registers (r3: spill), Bw NOT from global (r2: L2 thrash).
// ---------------------------------------------------------------------------
__global__ void __launch_bounds__(512, 1)
fused_lora(const float* __restrict__ tokens,
           const float* __restrict__ lora_a,
           const float* __restrict__ lora_b,
           const float* __restrict__ scaling,
           const float* __restrict__ outc,
           float* __restrict__ out) {
    __shared__ __align__(16) float Bw_s[8 * 2304];   // 72 KB
    __shared__ __align__(16) float As[8 * 768];      // 24 KB, transposed A

    int half  = blockIdx.x;        // 0..1
    int b     = blockIdx.y;        // 0..127
    int tid   = threadIdx.x;       // 0..511
    int lane  = tid & 63;
    int wave  = tid >> 6;          // 0..7

    int   sel  = (int)outc[OFF_SEL + b];
    float top1 = outc[OFF_EW + (long long)b * 8 + sel];
    float gs   = scaling[sel] * top1;

    // ---- Stage Bw[sel] (72 KB) into LDS, coalesced.
    const float4* Bw4g = (const float4*)(lora_b + (long long)sel * 8 * 2304);
    float4*       Bw4s = (float4*)Bw_s;
    for (int i = tid; i < 4608; i += 512) Bw4s[i] = Bw4g[i];

    // ---- Stage A[sel] ([d][r] layout) transposed into As[r][d].
    const float4* A4 = (const float4*)(lora_a + (long long)sel * 768 * 8);
    for (int f = tid; f < 1536; f += 512) {
        float4 g = A4[f];
        int d  = f >> 1;
        int r0 = (f & 1) * 4;
        As[(r0 + 0) * 768 + d] = g.x;
        As[(r0 + 1) * 768 + d] = g.y;
        As[(r0 + 2) * 768 + d] = g.z;
        As[(r0 + 3) * 768 + d] = g.w;
    }
    __syncthreads();   // only barrier in the kernel

    int t0 = half * 99;
    int t1 = t0 + 99; if (t1 > T_) t1 = T_;    // 99 rows / 98 rows

    // Wave w owns rows t0+w, t0+w+8, ... (stride 8).  Groups of 8 rows.
    for (int tg0 = t0 + wave; tg0 < t1; tg0 += 64) {
        int nr = (t1 - tg0 + 7) >> 3;          // valid rows in this group
        if (nr > 8) nr = 8;                    // wave-uniform

        // ---- h for up to 8 rows; butterfly gives every lane the sums.
        float hreg[8][8];
        #pragma unroll
        for (int r = 0; r < 8; ++r) {
            if (r < nr) {   // wave-uniform: shuffles safe inside
                int t = tg0 + 8 * r;
                const float4* tok4 =
                    (const float4*)(tokens + ((long long)b * T_ + t) * D_);
                float acc[8];
                #pragma unroll
                for (int j = 0; j < 8; ++j) acc[j] = 0.f;
                #pragma unroll
                for (int k = 0; k < 3; ++k) {
                    int d4 = lane + 64 * k;
                    float4 tv = tok4[d4];
                    #pragma unroll
                    for (int j = 0; j < 8; ++j) {
                        v4f ar = *(const v4f*)(As + j * 768 + d4 * 4);
                        acc[j] += tv.x * ar.x + tv.y * ar.y
                                + tv.z * ar.z + tv.w * ar.w;
                    }
                }
                #pragma unroll
                for (int off = 32; off > 0; off >>= 1) {
                    #pragma unroll
                    for (int j = 0; j < 8; ++j)
                        acc[j] += __shfl_xor(acc[j], off, 64);
                }
                #pragma unroll
                for (int j = 0; j < 8; ++j) hreg[r][j] = acc[j] * gs;
            }
        }

        // ---- WU for the same rows: one pass over Bw in LDS, 8 rows deep.
        #pragma unroll
        for (int k = 0; k < 9; ++k) {
            int o4 = lane + 64 * k;
            v4f accv[8];
            #pragma unroll
            for (int r = 0; r < 8; ++r) {
                accv[r].x = 0.f; accv[r].y = 0.f;
                accv[r].z = 0.f; accv[r].w = 0.f;
            }
            #pragma unroll
            for (int j = 0; j < 8; ++j) {
                v4f bv = ((const v4f*)Bw_s)[j * 576 + o4];
                #pragma unroll
                for (int r = 0; r < 8; ++r)
                    accv[r] += hreg[r][j] * bv;
            }
            #pragma unroll
            for (int r = 0; r < 8; ++r) {
                if (r < nr) {
                    v4f* orow =
                        (v4f*)(out + ((long long)b * T_ + (tg0 + 8 * r)) * O_);
                    __builtin_nontemporal_store(accv[r], &orow[o4]);
                }
            }
        }
    }
}

// ---------------------------------------------------------------------------
extern "C" void kernel_launch(void* const* d_in, const int* in_sizes, int n_in,
                              void* d_out, int out_size, void* d_ws, size_t ws_size,
                              hipStream_t stream) {
    const float* tokens  = (const float*)d_in[0];
    const float* w_gate  = (const float*)d_in[1];
    const float* lora_a  = (const float*)d_in[2];
    const float* lora_b  = (const float*)d_in[3];
    const float* scaling = (const float*)d_in[4];
    float* out = (float*)d_out;

    pool_partial<<<dim3(4, 128), 192, 0, stream>>>(tokens, out);
    route<<<128, 256, 0, stream>>>(out, w_gate, out);
    fused_lora<<<dim3(2, 128), 512, 0, stream>>>(tokens, lora_a, lora_b, scaling, out, out);
}

// Round 7
// 332.495 us; speedup vs baseline: 1.1348x; 1.1348x over previous
//
#include <hip/hip_runtime.h>

typedef float v4f __attribute__((ext_vector_type(4)));

// Problem constants
#define B_ 128
#define T_ 197
#define D_ 768
#define E_ 8
#define R_ 8
#define O_ 2304

// d_out flat layout (fp32 elements), in reference return order
#define NWU      (128LL * 197LL * 2304LL)      // weighted_update
#define OFF_RL   (NWU)                          // router_logits: 128*8
#define OFF_SEL  (OFF_RL + 1024LL)              // selected_experts: 128 (as float)
#define OFF_EW   (OFF_SEL + 128LL)              // expert_weights: 128*8
#define OFF_IMP  (OFF_EW + 1024LL)              // importance: 8
#define OFF_LOAD (OFF_IMP + 8LL)                // load: 8

// ---------------------------------------------------------------------------
// Kernel 1: partial token sums over T-chunks, float4-vectorized.
// partials live in the WU region of d_out (consumed by `route` before
// fused_lora overwrites the region).  part[(b*4+c)*768 + d]
// Also zero-inits the importance/load accumulators (16 floats).
// ---------------------------------------------------------------------------
__global__ void pool_partial(const float* __restrict__ tokens,
                             float* __restrict__ out) {
    int c   = blockIdx.x;          // 0..3
    int b   = blockIdx.y;          // 0..127
    int tid = threadIdx.x;         // 0..191  (float4 column)
    if (c == 0 && b == 0 && tid < 16) out[OFF_IMP + tid] = 0.0f;
    int t0 = c * 50;
    int t1 = t0 + 50; if (t1 > T_) t1 = T_;
    const float4* tp = (const float4*)(tokens + (long long)b * T_ * D_);
    float4 acc; acc.x = 0.f; acc.y = 0.f; acc.z = 0.f; acc.w = 0.f;
    for (int t = t0; t < t1; ++t) {
        float4 v = tp[t * 192 + tid];
        acc.x += v.x; acc.y += v.y; acc.z += v.z; acc.w += v.w;
    }
    ((float4*)out)[(long long)(b * 4 + c) * 192 + tid] = acc;
}

// ---------------------------------------------------------------------------
// Kernel 2: routing + stats.  One block per batch row.
// stats (importance/load) folded in via device-scope atomicAdd.
// ---------------------------------------------------------------------------
__global__ void route(const float* __restrict__ part,
                      const float* __restrict__ w_gate,
                      float* __restrict__ out) {
    __shared__ float pooled[768];
    __shared__ float psum[64];
    __shared__ float logits[8];
    __shared__ int   sel_s;
    __shared__ float top1_s;
    __shared__ float m_s, inv_s;

    int b   = blockIdx.x;
    int tid = threadIdx.x;

    #pragma unroll
    for (int j = 0; j < 3; ++j) {
        int d = tid + j * 256;
        float s = part[(long long)(b * 4 + 0) * D_ + d]
                + part[(long long)(b * 4 + 1) * D_ + d]
                + part[(long long)(b * 4 + 2) * D_ + d]
                + part[(long long)(b * 4 + 3) * D_ + d];
        pooled[d] = s * (1.0f / 197.0f);
    }
    __syncthreads();

    if (tid < 64) {
        int e = tid & 7;
        int p = tid >> 3;
        float s = 0.f;
        int d0 = p * 96;
        for (int d = d0; d < d0 + 96; ++d) s += pooled[d] * w_gate[d * 8 + e];
        psum[tid] = s;
    }
    __syncthreads();

    if (tid < 8) {
        float s = 0.f;
        #pragma unroll
        for (int p = 0; p < 8; ++p) s += psum[p * 8 + tid];
        logits[tid] = s;
        out[OFF_RL + (long long)b * 8 + tid] = s;
    }
    __syncthreads();

    if (tid == 0) {
        float m = logits[0];
        int sel = 0;
        #pragma unroll
        for (int e = 1; e < 8; ++e)
            if (logits[e] > m) { m = logits[e]; sel = e; }   // first max wins
        float den = 0.f;
        #pragma unroll
        for (int e = 0; e < 8; ++e) den += expf(logits[e] - m);
        float t1v = 1.0f / den;
        sel_s  = sel;
        top1_s = t1v;
        m_s    = m;
        inv_s  = t1v;
        out[OFF_SEL + b] = (float)sel;
        atomicAdd(&out[OFF_IMP + sel], t1v);     // importance[sel] += top1
    }
    __syncthreads();

    if (tid < 8) {
        out[OFF_EW + (long long)b * 8 + tid] = (tid == sel_s) ? top1_s : 0.0f;
        // load[e] += softmax(logits)[e]
        atomicAdd(&out[OFF_LOAD + tid], expf(logits[tid] - m_s) * inv_s);
    }
}

// ---------------------------------------------------------------------------
// Kernel 3: fused  h = (tokens @ A[sel]) * gs  →  regs  →  wu = h @ Bw[sel].
//
// REVERTED to the round-5 configuration (333 µs best).  Round-6's 8-row
// groups regressed (+44 µs): hreg[8][8]+accv[8] pushed peak VGPR pressure
// to the 2-wave/SIMD cap and the longer serial h-phase per group halved
// the read/write alternation frequency that keeps both HBM directions
// busy.  Design space now bracketed on every axis:
//  - group depth: 2-phase (r1) > 4-deep (r5, BEST) < 8-deep (r6)
//  - Bw: global (r2, L2 thrash) < LDS;  A: registers (r3, spill) < LDS
//  - grid: 512 blocks (r4) < 256 blocks = 1/CU (r5)
// Structure: As+Bw co-resident in 96 KB LDS, staged once per CU; h in
// registers via __shfl_xor butterfly; per-wave 4-row pipeline interleaving
// token reads with NT WU stores; single barrier.
// ---------------------------------------------------------------------------
__global__ void __launch_bounds__(512, 1)
fused_lora(const float* __restrict__ tokens,
           const float* __restrict__ lora_a,
           const float* __restrict__ lora_b,
           const float* __restrict__ scaling,
           const float* __restrict__ outc,
           float* __restrict__ out) {
    __shared__ __align__(16) float Bw_s[8 * 2304];   // 72 KB
    __shared__ __align__(16) float As[8 * 768];      // 24 KB, transposed A

    int half  = blockIdx.x;        // 0..1
    int b     = blockIdx.y;        // 0..127
    int tid   = threadIdx.x;       // 0..511
    int lane  = tid & 63;
    int wave  = tid >> 6;          // 0..7

    int   sel  = (int)outc[OFF_SEL + b];
    float top1 = outc[OFF_EW + (long long)b * 8 + sel];
    float gs   = scaling[sel] * top1;

    // ---- Stage Bw[sel] (72 KB) into LDS, coalesced.
    const float4* Bw4g = (const float4*)(lora_b + (long long)sel * 8 * 2304);
    float4*       Bw4s = (float4*)Bw_s;
    for (int i = tid; i < 4608; i += 512) Bw4s[i] = Bw4g[i];

    // ---- Stage A[sel] ([d][r] layout) transposed into As[r][d].
    const float4* A4 = (const float4*)(lora_a + (long long)sel * 768 * 8);
    for (int f = tid; f < 1536; f += 512) {
        float4 g = A4[f];
        int d  = f >> 1;
        int r0 = (f & 1) * 4;
        As[(r0 + 0) * 768 + d] = g.x;
        As[(r0 + 1) * 768 + d] = g.y;
        As[(r0 + 2) * 768 + d] = g.z;
        As[(r0 + 3) * 768 + d] = g.w;
    }
    __syncthreads();   // only barrier in the kernel

    int t0 = half * 99;
    int t1 = t0 + 99; if (t1 > T_) t1 = T_;    // 99 rows / 98 rows

    // Wave w owns rows t0+w, t0+w+8, ...  Process 4 at a time (stride 8).
    for (int tg0 = t0 + wave; tg0 < t1; tg0 += 32) {
        int nr = (t1 - tg0 + 7) >> 3;          // valid rows in this group
        if (nr > 4) nr = 4;                    // wave-uniform

        // ---- h for up to 4 rows; butterfly gives every lane the sums.
        float hreg[4][8];
        #pragma unroll
        for (int r = 0; r < 4; ++r) {
            if (r < nr) {   // wave-uniform: shuffles safe inside
                int t = tg0 + 8 * r;
                const float4* tok4 =
                    (const float4*)(tokens + ((long long)b * T_ + t) * D_);
                float acc[8];
                #pragma unroll
                for (int j = 0; j < 8; ++j) acc[j] = 0.f;
                #pragma unroll
                for (int k = 0; k < 3; ++k) {
                    int d4 = lane + 64 * k;
                    float4 tv = tok4[d4];
                    #pragma unroll
                    for (int j = 0; j < 8; ++j) {
                        v4f ar = *(const v4f*)(As + j * 768 + d4 * 4);
                        acc[j] += tv.x * ar.x + tv.y * ar.y
                                + tv.z * ar.z + tv.w * ar.w;
                    }
                }
                #pragma unroll
                for (int off = 32; off > 0; off >>= 1) {
                    #pragma unroll
                    for (int j = 0; j < 8; ++j)
                        acc[j] += __shfl_xor(acc[j], off, 64);
                }
                #pragma unroll
                for (int j = 0; j < 8; ++j) hreg[r][j] = acc[j] * gs;
            }
        }

        // ---- WU for the same rows: one pass over Bw in LDS, 4 rows deep.
        #pragma unroll
        for (int k = 0; k < 9; ++k) {
            int o4 = lane + 64 * k;
            v4f acc0, acc1, acc2, acc3;
            acc0.x = 0.f; acc0.y = 0.f; acc0.z = 0.f; acc0.w = 0.f;
            acc1 = acc0; acc2 = acc0; acc3 = acc0;
            #pragma unroll
            for (int j = 0; j < 8; ++j) {
                v4f bv = ((const v4f*)Bw_s)[j * 576 + o4];
                acc0 += hreg[0][j] * bv;
                acc1 += hreg[1][j] * bv;
                acc2 += hreg[2][j] * bv;
                acc3 += hreg[3][j] * bv;
            }
            {
                v4f* o0 = (v4f*)(out + ((long long)b * T_ + (tg0 + 0)) * O_);
                __builtin_nontemporal_store(acc0, &o0[o4]);
            }
            if (nr > 1) {
                v4f* o1 = (v4f*)(out + ((long long)b * T_ + (tg0 + 8)) * O_);
                __builtin_nontemporal_store(acc1, &o1[o4]);
            }
            if (nr > 2) {
                v4f* o2 = (v4f*)(out + ((long long)b * T_ + (tg0 + 16)) * O_);
                __builtin_nontemporal_store(acc2, &o2[o4]);
            }
            if (nr > 3) {
                v4f* o3 = (v4f*)(out + ((long long)b * T_ + (tg0 + 24)) * O_);
                __builtin_nontemporal_store(acc3, &o3[o4]);
            }
        }
    }
}

// ---------------------------------------------------------------------------
extern "C" void kernel_launch(void* const* d_in, const int* in_sizes, int n_in,
                              void* d_out, int out_size, void* d_ws, size_t ws_size,
                              hipStream_t stream) {
    const float* tokens  = (const float*)d_in[0];
    const float* w_gate  = (const float*)d_in[1];
    const float* lora_a  = (const float*)d_in[2];
    const float* lora_b  = (const float*)d_in[3];
    const float* scaling = (const float*)d_in[4];
    float* out = (float*)d_out;

    pool_partial<<<dim3(4, 128), 192, 0, stream>>>(tokens, out);
    route<<<128, 256, 0, stream>>>(out, w_gate, out);
    fused_lora<<<dim3(2, 128), 512, 0, stream>>>(tokens, lora_a, lora_b, scaling, out, out);
}